// Round 7
// baseline (194.126 us; speedup 1.0000x reference)
//
#include <hip/hip_runtime.h>
#include <math.h>

#define BB 32
#define VV 2048
#define PP 64
#define AA 8
#define NFF 128
#define FF 72          // P + A
#define TWOF 144       // 2*F

// ---------------------------------------------------------------------------
// k1: feats = [x@W1+b1, exp(-|x@W2+b2|)]  -> featsT [B][F][V], agg [B][V][A]
// one thread per vertex, full 72-feature output. Weights read directly from
// global with wave-uniform addresses -> scalar (s_load) path, no LDS, no bar.
// ---------------------------------------------------------------------------
__global__ __launch_bounds__(256) void k1_feats(
        const float* __restrict__ x,
        const float* __restrict__ W1, const float* __restrict__ b1,
        const float* __restrict__ W2, const float* __restrict__ b2,
        float* __restrict__ featsT, float* __restrict__ agg) {
    const int b = blockIdx.y;
    const int v = blockIdx.x * 256 + threadIdx.x;

    // x row in registers (compile-time indexed only)
    float xs[64];
    const float4* xp = reinterpret_cast<const float4*>(x + ((size_t)b * VV + v) * PP);
    #pragma unroll
    for (int i = 0; i < 16; ++i) {
        float4 t = xp[i];
        xs[4 * i + 0] = t.x; xs[4 * i + 1] = t.y; xs[4 * i + 2] = t.z; xs[4 * i + 3] = t.w;
    }

    // vi chunks c = 0..15 (f = 4c..4c+3); W1[p][f] uniform -> scalar loads
    #pragma unroll 1
    for (int c = 0; c < 16; ++c) {
        float4 acc = make_float4(b1[4 * c + 0], b1[4 * c + 1], b1[4 * c + 2], b1[4 * c + 3]);
        #pragma unroll
        for (int p = 0; p < 64; ++p) {
            const float4 w = *reinterpret_cast<const float4*>(&W1[p * 64 + 4 * c]);
            const float xv = xs[p];
            acc.x += xv * w.x; acc.y += xv * w.y; acc.z += xv * w.z; acc.w += xv * w.w;
        }
        float* fr = featsT + ((size_t)b * FF + 4 * c) * VV + v;
        fr[0 * VV] = acc.x; fr[1 * VV] = acc.y; fr[2 * VV] = acc.z; fr[3 * VV] = acc.w;
    }

    // agg chunks (f = 64..71): W2[p][a] uniform -> scalar loads
    float ex[8];
    #pragma unroll 1
    for (int cc = 0; cc < 2; ++cc) {
        float4 acc = make_float4(b2[4 * cc + 0], b2[4 * cc + 1], b2[4 * cc + 2], b2[4 * cc + 3]);
        #pragma unroll
        for (int p = 0; p < 64; ++p) {
            const float4 w = *reinterpret_cast<const float4*>(&W2[p * 8 + 4 * cc]);
            const float xv = xs[p];
            acc.x += xv * w.x; acc.y += xv * w.y; acc.z += xv * w.z; acc.w += xv * w.w;
        }
        acc.x = __expf(-fabsf(acc.x));
        acc.y = __expf(-fabsf(acc.y));
        acc.z = __expf(-fabsf(acc.z));
        acc.w = __expf(-fabsf(acc.w));
        float* fr = featsT + ((size_t)b * FF + 64 + 4 * cc) * VV + v;
        fr[0 * VV] = acc.x; fr[1 * VV] = acc.y; fr[2 * VV] = acc.z; fr[3 * VV] = acc.w;
        ex[4 * cc + 0] = acc.x; ex[4 * cc + 1] = acc.y; ex[4 * cc + 2] = acc.z; ex[4 * cc + 3] = acc.w;
    }

    float4* ap = reinterpret_cast<float4*>(agg + ((size_t)b * VV + v) * AA);
    ap[0] = make_float4(ex[0], ex[1], ex[2], ex[3]);
    ap[1] = make_float4(ex[4], ex[5], ex[6], ex[7]);
}

// ---------------------------------------------------------------------------
// k2: reduce over V: mx/mn of agg[b,v,a]*feats[b,v,f] -> collapsed [B][A][2F]
// (unchanged from round 6 — control; awaiting its first profile appearance)
// ---------------------------------------------------------------------------
__global__ __launch_bounds__(256) void k2_reduce(
        const float* __restrict__ featsT, const float* __restrict__ agg,
        float* __restrict__ collapsed) {
    const int fg = blockIdx.x;      // 0..17
    const int b  = blockIdx.y;
    const int f0 = fg * 4;
    const int t  = threadIdx.x;
    const int wave = t >> 6, lane = t & 63;

    __shared__ float redm[4][32];
    __shared__ float reds[4][32];

    float pmax[4][8], psum[4][8];
    #pragma unroll
    for (int j = 0; j < 4; ++j)
        #pragma unroll
        for (int a = 0; a < 8; ++a) { pmax[j][a] = -INFINITY; psum[j][a] = 0.0f; }

    for (int i = 0; i < 8; ++i) {
        const int v = i * 256 + t;
        const float4* ep = reinterpret_cast<const float4*>(agg + ((size_t)b * VV + v) * AA);
        const float4 e0 = ep[0], e1 = ep[1];
        float e[8];
        e[0] = e0.x; e[1] = e0.y; e[2] = e0.z; e[3] = e0.w;
        e[4] = e1.x; e[5] = e1.y; e[6] = e1.z; e[7] = e1.w;
        #pragma unroll
        for (int j = 0; j < 4; ++j) {
            const float fv = featsT[((size_t)b * FF + f0 + j) * VV + v];
            #pragma unroll
            for (int a = 0; a < 8; ++a) {
                const float pr = e[a] * fv;
                pmax[j][a] = fmaxf(pmax[j][a], pr);
                psum[j][a] += pr;
            }
        }
    }

    #pragma unroll
    for (int j = 0; j < 4; ++j) {
        #pragma unroll
        for (int a = 0; a < 8; ++a) {
            float m = pmax[j][a];
            float s = psum[j][a];
            #pragma unroll
            for (int d = 1; d < 64; d <<= 1) {
                m = fmaxf(m, __shfl_xor(m, d));
                s += __shfl_xor(s, d);
            }
            if (lane == 0) { redm[wave][j * 8 + a] = m; reds[wave][j * 8 + a] = s; }
        }
    }
    __syncthreads();

    if (t < 32) {
        const int j = t >> 3, a = t & 7;
        float m = redm[0][t], s = reds[0][t];
        #pragma unroll
        for (int w = 1; w < 4; ++w) { m = fmaxf(m, redm[w][t]); s += reds[w][t]; }
        float* cr = collapsed + ((size_t)b * AA + a) * TWOF;
        cr[f0 + j]      = m;
        cr[FF + f0 + j] = s * (1.0f / (float)VV);
    }
}

// ---------------------------------------------------------------------------
// k2b: M'[b][a][nf] = Wout[1216+a][nf] + sum_g collapsed[b][a][g]*Wout[64+a*144+g][nf]
// 256 threads: g-range split x2 (t>>7), nf = t&127; col[g] scalar, Wout coalesced
// ---------------------------------------------------------------------------
__global__ __launch_bounds__(256) void k2b_mprime(
        const float* __restrict__ collapsed, const float* __restrict__ Wout,
        float* __restrict__ Mp) {
    const int a = blockIdx.x, b = blockIdx.y;
    const int t = threadIdx.x;
    const int nf = t & 127, gh = t >> 7;     // gh = 0/1
    __shared__ float part[2][128];

    const float* col  = collapsed + ((size_t)b * AA + a) * TWOF;
    const float* Wexp = Wout + (size_t)(64 + a * TWOF) * NFF;

    float acc = 0.0f;
    const int g0 = gh * 72;
    #pragma unroll 8
    for (int g = g0; g < g0 + 72; ++g)
        acc += col[g] * Wexp[(size_t)g * NFF + nf];
    part[gh][nf] = acc;
    __syncthreads();

    if (t < 128) {
        float r = part[0][t] + part[1][t] + Wout[(size_t)(1216 + a) * NFF + t];
        Mp[((size_t)b * AA + a) * NFF + t] = r;
    }
}

// ---------------------------------------------------------------------------
// k3: out = tanh(x@Wtop + agg@M'[b] + bout)  -> [B][V][NF]
// one thread per vertex, full 128-nf row (512-B contiguous store -> exact
// WRITE_SIZE). Wout/Mp/bout read with wave-uniform addresses -> scalar path.
// ---------------------------------------------------------------------------
__device__ __forceinline__ float fast_tanh(float z) {
    const float e = __expf(2.0f * z);
    return 1.0f - 2.0f / (e + 1.0f);
}

__global__ __launch_bounds__(256) void k3_out(
        const float* __restrict__ x, const float* __restrict__ agg,
        const float* __restrict__ Mp, const float* __restrict__ Wout,
        const float* __restrict__ bout, float* __restrict__ out) {
    const int b = blockIdx.y;
    const int v = blockIdx.x * 256 + threadIdx.x;

    float xs[64];
    const float4* xp = reinterpret_cast<const float4*>(x + ((size_t)b * VV + v) * PP);
    #pragma unroll
    for (int i = 0; i < 16; ++i) {
        float4 t = xp[i];
        xs[4 * i + 0] = t.x; xs[4 * i + 1] = t.y; xs[4 * i + 2] = t.z; xs[4 * i + 3] = t.w;
    }
    float e[8];
    const float4* ep = reinterpret_cast<const float4*>(agg + ((size_t)b * VV + v) * AA);
    {
        const float4 e0 = ep[0], e1 = ep[1];
        e[0] = e0.x; e[1] = e0.y; e[2] = e0.z; e[3] = e0.w;
        e[4] = e1.x; e[5] = e1.y; e[6] = e1.z; e[7] = e1.w;
    }

    const float* Mpb = Mp + (size_t)b * AA * NFF;
    float4* op = reinterpret_cast<float4*>(out + ((size_t)b * VV + v) * NFF);

    #pragma unroll 1
    for (int c = 0; c < 32; ++c) {
        float4 acc = make_float4(bout[4 * c + 0], bout[4 * c + 1],
                                 bout[4 * c + 2], bout[4 * c + 3]);
        #pragma unroll
        for (int p = 0; p < 64; ++p) {
            const float4 w = *reinterpret_cast<const float4*>(&Wout[(size_t)p * NFF + 4 * c]);
            const float xv = xs[p];
            acc.x += xv * w.x; acc.y += xv * w.y; acc.z += xv * w.z; acc.w += xv * w.w;
        }
        #pragma unroll
        for (int a = 0; a < 8; ++a) {
            const float4 w = *reinterpret_cast<const float4*>(&Mpb[(size_t)a * NFF + 4 * c]);
            const float ea = e[a];
            acc.x += ea * w.x; acc.y += ea * w.y; acc.z += ea * w.z; acc.w += ea * w.w;
        }
        acc.x = fast_tanh(acc.x); acc.y = fast_tanh(acc.y);
        acc.z = fast_tanh(acc.z); acc.w = fast_tanh(acc.w);
        op[c] = acc;
    }
}

// ---------------------------------------------------------------------------
extern "C" void kernel_launch(void* const* d_in, const int* in_sizes, int n_in,
                              void* d_out, int out_size, void* d_ws, size_t ws_size,
                              hipStream_t stream) {
    const float* x    = (const float*)d_in[0];
    const float* W1   = (const float*)d_in[1];
    const float* b1   = (const float*)d_in[2];
    const float* W2   = (const float*)d_in[3];
    const float* b2   = (const float*)d_in[4];
    const float* Wout = (const float*)d_in[5];
    const float* bout = (const float*)d_in[6];
    float* out = (float*)d_out;

    float* ws     = (float*)d_ws;
    float* featsT = ws;                                   // B*F*V   = 4,718,592
    float* agg    = featsT + (size_t)BB * FF * VV;        // B*V*A   =   524,288
    float* coll   = agg + (size_t)BB * VV * AA;           // B*A*2F  =    36,864
    float* Mp     = coll + (size_t)BB * AA * TWOF;        // B*A*NF  =    32,768

    k1_feats<<<dim3(8, 32), dim3(256), 0, stream>>>(x, W1, b1, W2, b2, featsT, agg);
    k2_reduce<<<dim3(18, 32), dim3(256), 0, stream>>>(featsT, agg, coll);
    k2b_mprime<<<dim3(8, 32), dim3(256), 0, stream>>>(coll, Wout, Mp);
    k3_out<<<dim3(8, 32), dim3(256), 0, stream>>>(x, agg, Mp, Wout, bout, out);
}

// Round 8
// 169.925 us; speedup vs baseline: 1.1424x; 1.1424x over previous
//
#include <hip/hip_runtime.h>
#include <math.h>

#define BB 32
#define VV 2048
#define PP 64
#define AA 8
#define NFF 128
#define FF 72          // P + A
#define TWOF 144       // 2*F

// ---------------------------------------------------------------------------
// k1: feats = [x@W1+b1, exp(-|x@W2+b2|)]  -> featsT [B][F][V], agg [B][V][A]
// block = 256 thr: wave w owns float4-chunks c = w+4k (k=0..4); lane = vertex.
// Weights via wave-uniform scalar loads; 1024 blocks for occupancy.
// ---------------------------------------------------------------------------
__global__ __launch_bounds__(256) void k1_feats(
        const float* __restrict__ x,
        const float* __restrict__ W1, const float* __restrict__ b1,
        const float* __restrict__ W2, const float* __restrict__ b2,
        float* __restrict__ featsT, float* __restrict__ agg) {
    const int b    = blockIdx.y;
    const int t    = threadIdx.x;
    const int w    = __builtin_amdgcn_readfirstlane(t >> 6);  // wave id, uniform
    const int lane = t & 63;
    const int v    = blockIdx.x * 64 + lane;

    // x row in registers (compile-time indexed only)
    float xs[64];
    const float4* xp = reinterpret_cast<const float4*>(x + ((size_t)b * VV + v) * PP);
    #pragma unroll
    for (int i = 0; i < 16; ++i) {
        float4 t4 = xp[i];
        xs[4 * i + 0] = t4.x; xs[4 * i + 1] = t4.y; xs[4 * i + 2] = t4.z; xs[4 * i + 3] = t4.w;
    }

    #pragma unroll 1
    for (int k = 0; k < 5; ++k) {
        const int c = w + 4 * k;           // uniform across wave
        if (c >= 18) break;                // uniform branch (w=2,3 do 4 iters)
        const int f0 = 4 * c;
        float4 acc;
        if (c < 16) {
            acc = make_float4(b1[f0 + 0], b1[f0 + 1], b1[f0 + 2], b1[f0 + 3]);
            #pragma unroll
            for (int p = 0; p < 64; ++p) {
                const float4 wt = *reinterpret_cast<const float4*>(&W1[p * 64 + f0]);
                const float xv = xs[p];
                acc.x += xv * wt.x; acc.y += xv * wt.y; acc.z += xv * wt.z; acc.w += xv * wt.w;
            }
        } else {
            const int a0 = f0 - 64;        // 0 or 4
            acc = make_float4(b2[a0 + 0], b2[a0 + 1], b2[a0 + 2], b2[a0 + 3]);
            #pragma unroll
            for (int p = 0; p < 64; ++p) {
                const float4 wt = *reinterpret_cast<const float4*>(&W2[p * 8 + a0]);
                const float xv = xs[p];
                acc.x += xv * wt.x; acc.y += xv * wt.y; acc.z += xv * wt.z; acc.w += xv * wt.w;
            }
            acc.x = __expf(-fabsf(acc.x));
            acc.y = __expf(-fabsf(acc.y));
            acc.z = __expf(-fabsf(acc.z));
            acc.w = __expf(-fabsf(acc.w));
            float4* ap = reinterpret_cast<float4*>(agg + ((size_t)b * VV + v) * AA);
            ap[c - 16] = acc;              // c==16 -> a0..3, c==17 -> a4..7
        }
        float* fr = featsT + ((size_t)b * FF + f0) * VV + v;
        fr[0 * VV] = acc.x; fr[1 * VV] = acc.y; fr[2 * VV] = acc.z; fr[3 * VV] = acc.w;
    }
}

// ---------------------------------------------------------------------------
// k2: reduce over V: mx/mn of agg[b,v,a]*feats[b,v,f] -> collapsed [B][A][2F]
// (unchanged — control; becomes top dispatch this round for first profile)
// ---------------------------------------------------------------------------
__global__ __launch_bounds__(256) void k2_reduce(
        const float* __restrict__ featsT, const float* __restrict__ agg,
        float* __restrict__ collapsed) {
    const int fg = blockIdx.x;      // 0..17
    const int b  = blockIdx.y;
    const int f0 = fg * 4;
    const int t  = threadIdx.x;
    const int wave = t >> 6, lane = t & 63;

    __shared__ float redm[4][32];
    __shared__ float reds[4][32];

    float pmax[4][8], psum[4][8];
    #pragma unroll
    for (int j = 0; j < 4; ++j)
        #pragma unroll
        for (int a = 0; a < 8; ++a) { pmax[j][a] = -INFINITY; psum[j][a] = 0.0f; }

    for (int i = 0; i < 8; ++i) {
        const int v = i * 256 + t;
        const float4* ep = reinterpret_cast<const float4*>(agg + ((size_t)b * VV + v) * AA);
        const float4 e0 = ep[0], e1 = ep[1];
        float e[8];
        e[0] = e0.x; e[1] = e0.y; e[2] = e0.z; e[3] = e0.w;
        e[4] = e1.x; e[5] = e1.y; e[6] = e1.z; e[7] = e1.w;
        #pragma unroll
        for (int j = 0; j < 4; ++j) {
            const float fv = featsT[((size_t)b * FF + f0 + j) * VV + v];
            #pragma unroll
            for (int a = 0; a < 8; ++a) {
                const float pr = e[a] * fv;
                pmax[j][a] = fmaxf(pmax[j][a], pr);
                psum[j][a] += pr;
            }
        }
    }

    #pragma unroll
    for (int j = 0; j < 4; ++j) {
        #pragma unroll
        for (int a = 0; a < 8; ++a) {
            float m = pmax[j][a];
            float s = psum[j][a];
            #pragma unroll
            for (int d = 1; d < 64; d <<= 1) {
                m = fmaxf(m, __shfl_xor(m, d));
                s += __shfl_xor(s, d);
            }
            if (lane == 0) { redm[wave][j * 8 + a] = m; reds[wave][j * 8 + a] = s; }
        }
    }
    __syncthreads();

    if (t < 32) {
        const int j = t >> 3, a = t & 7;
        float m = redm[0][t], s = reds[0][t];
        #pragma unroll
        for (int w = 1; w < 4; ++w) { m = fmaxf(m, redm[w][t]); s += reds[w][t]; }
        float* cr = collapsed + ((size_t)b * AA + a) * TWOF;
        cr[f0 + j]      = m;
        cr[FF + f0 + j] = s * (1.0f / (float)VV);
    }
}

// ---------------------------------------------------------------------------
// k2b: M'[b][a][nf] = Wout[1216+a][nf] + sum_g collapsed[b][a][g]*Wout[64+a*144+g][nf]
// ---------------------------------------------------------------------------
__global__ __launch_bounds__(256) void k2b_mprime(
        const float* __restrict__ collapsed, const float* __restrict__ Wout,
        float* __restrict__ Mp) {
    const int a = blockIdx.x, b = blockIdx.y;
    const int t = threadIdx.x;
    const int nf = t & 127, gh = t >> 7;     // gh = 0/1
    __shared__ float part[2][128];

    const float* col  = collapsed + ((size_t)b * AA + a) * TWOF;
    const float* Wexp = Wout + (size_t)(64 + a * TWOF) * NFF;

    float acc = 0.0f;
    const int g0 = gh * 72;
    #pragma unroll 8
    for (int g = g0; g < g0 + 72; ++g)
        acc += col[g] * Wexp[(size_t)g * NFF + nf];
    part[gh][nf] = acc;
    __syncthreads();

    if (t < 128) {
        float r = part[0][t] + part[1][t] + Wout[(size_t)(1216 + a) * NFF + t];
        Mp[((size_t)b * AA + a) * NFF + t] = r;
    }
}

// ---------------------------------------------------------------------------
// k3: out = tanh(x@Wtop + agg@M'[b] + bout)  -> [B][V][NF]
// block = 256 thr: wave q owns nf columns q*32..q*32+31; lane = vertex.
// Each thread writes one full 128-B line -> exact WRITE_SIZE by construction.
// Weights via wave-uniform scalar loads; 1024 blocks for occupancy.
// ---------------------------------------------------------------------------
__device__ __forceinline__ float fast_tanh(float z) {
    const float e = __expf(2.0f * z);
    return 1.0f - 2.0f / (e + 1.0f);
}

__global__ __launch_bounds__(256) void k3_out(
        const float* __restrict__ x, const float* __restrict__ agg,
        const float* __restrict__ Mp, const float* __restrict__ Wout,
        const float* __restrict__ bout, float* __restrict__ out) {
    const int b    = blockIdx.y;
    const int t    = threadIdx.x;
    const int q    = __builtin_amdgcn_readfirstlane(t >> 6);  // nf-quarter, uniform
    const int lane = t & 63;
    const int v    = blockIdx.x * 64 + lane;
    const int n0   = q * 32;

    float xs[64];
    const float4* xp = reinterpret_cast<const float4*>(x + ((size_t)b * VV + v) * PP);
    #pragma unroll
    for (int i = 0; i < 16; ++i) {
        float4 t4 = xp[i];
        xs[4 * i + 0] = t4.x; xs[4 * i + 1] = t4.y; xs[4 * i + 2] = t4.z; xs[4 * i + 3] = t4.w;
    }
    float e[8];
    const float4* ep = reinterpret_cast<const float4*>(agg + ((size_t)b * VV + v) * AA);
    {
        const float4 e0 = ep[0], e1 = ep[1];
        e[0] = e0.x; e[1] = e0.y; e[2] = e0.z; e[3] = e0.w;
        e[4] = e1.x; e[5] = e1.y; e[6] = e1.z; e[7] = e1.w;
    }

    const float* Wq  = Wout + n0;                       // rows 0..63, col slice
    const float* Mpq = Mp + (size_t)b * AA * NFF + n0;
    const float* bq  = bout + n0;
    float* op = out + ((size_t)b * VV + v) * NFF + n0;

    #pragma unroll 1
    for (int cc = 0; cc < 8; ++cc) {
        float4 acc = make_float4(bq[4 * cc + 0], bq[4 * cc + 1],
                                 bq[4 * cc + 2], bq[4 * cc + 3]);
        #pragma unroll
        for (int p = 0; p < 64; ++p) {
            const float4 wt = *reinterpret_cast<const float4*>(&Wq[(size_t)p * NFF + 4 * cc]);
            const float xv = xs[p];
            acc.x += xv * wt.x; acc.y += xv * wt.y; acc.z += xv * wt.z; acc.w += xv * wt.w;
        }
        #pragma unroll
        for (int a = 0; a < 8; ++a) {
            const float4 wt = *reinterpret_cast<const float4*>(&Mpq[(size_t)a * NFF + 4 * cc]);
            const float ea = e[a];
            acc.x += ea * wt.x; acc.y += ea * wt.y; acc.z += ea * wt.z; acc.w += ea * wt.w;
        }
        acc.x = fast_tanh(acc.x); acc.y = fast_tanh(acc.y);
        acc.z = fast_tanh(acc.z); acc.w = fast_tanh(acc.w);
        *reinterpret_cast<float4*>(&op[4 * cc]) = acc;
    }
}

// ---------------------------------------------------------------------------
extern "C" void kernel_launch(void* const* d_in, const int* in_sizes, int n_in,
                              void* d_out, int out_size, void* d_ws, size_t ws_size,
                              hipStream_t stream) {
    const float* x    = (const float*)d_in[0];
    const float* W1   = (const float*)d_in[1];
    const float* b1   = (const float*)d_in[2];
    const float* W2   = (const float*)d_in[3];
    const float* b2   = (const float*)d_in[4];
    const float* Wout = (const float*)d_in[5];
    const float* bout = (const float*)d_in[6];
    float* out = (float*)d_out;

    float* ws     = (float*)d_ws;
    float* featsT = ws;                                   // B*F*V   = 4,718,592
    float* agg    = featsT + (size_t)BB * FF * VV;        // B*V*A   =   524,288
    float* coll   = agg + (size_t)BB * VV * AA;           // B*A*2F  =    36,864
    float* Mp     = coll + (size_t)BB * AA * TWOF;        // B*A*NF  =    32,768

    k1_feats<<<dim3(32, 32), dim3(256), 0, stream>>>(x, W1, b1, W2, b2, featsT, agg);
    k2_reduce<<<dim3(18, 32), dim3(256), 0, stream>>>(featsT, agg, coll);
    k2b_mprime<<<dim3(8, 32), dim3(256), 0, stream>>>(coll, Wout, Mp);
    k3_out<<<dim3(32, 32), dim3(256), 0, stream>>>(x, agg, Mp, Wout, bout, out);
}